// Round 10
// baseline (151.247 us; speedup 1.0000x reference)
//
#include <hip/hip_runtime.h>

typedef unsigned short u16;
typedef __bf16 bf16x8 __attribute__((ext_vector_type(8)));
typedef float f32x4 __attribute__((ext_vector_type(4)));
typedef unsigned short u16x8 __attribute__((ext_vector_type(8)));
typedef unsigned short u16x4 __attribute__((ext_vector_type(4)));

union B8 { u16x8 u; bf16x8 b; };

#define MFMA_BF16(a, b, c) __builtin_amdgcn_mfma_f32_16x16x32_bf16((a), (b), (c), 0, 0, 0)

__device__ __forceinline__ u16 f2bf(float f) {
  unsigned x = __float_as_uint(f);
  unsigned r = x + 0x7fffu + ((x >> 16) & 1u);
  return (u16)(r >> 16);
}

__device__ __forceinline__ unsigned cvt_pk_bf16(float lo, float hi) {
  unsigned r;
  asm("v_cvt_pk_bf16_f32 %0, %1, %2" : "=v"(r) : "v"(lo), "v"(hi));
  return r;
}

__device__ __forceinline__ void gl2lds16(const void* g, void* l) {
  __builtin_amdgcn_global_load_lds(
      (const __attribute__((address_space(1))) void*)g,
      (__attribute__((address_space(3))) void*)l, 16, 0, 0);
}

// ---------------- cast f32 -> bf16 (X, Wq, Wk, Wv, Wp) ----------------
__global__ __launch_bounds__(256) void cast5_kernel(
    const float* __restrict__ X, const float* __restrict__ Wq,
    const float* __restrict__ Wk, const float* __restrict__ Wv,
    const float* __restrict__ Wp, u16* __restrict__ Xb, u16* __restrict__ Wqb,
    u16* __restrict__ Wkb, u16* __restrict__ Wvb, u16* __restrict__ Wpb) {
  size_t i = ((size_t)blockIdx.x * 256 + threadIdx.x) * 4;
  const float* src;
  u16* dst;
  size_t off;
  if (i < 4194304) {
    src = X; dst = Xb; off = i;
  } else if (i < 5242880) {
    src = Wq; dst = Wqb; off = i - 4194304;
  } else if (i < 6291456) {
    src = Wk; dst = Wkb; off = i - 5242880;
  } else if (i < 7340032) {
    src = Wv; dst = Wvb; off = i - 6291456;
  } else {
    src = Wp; dst = Wpb; off = i - 7340032;
  }
  float4 v = *(const float4*)(src + off);
  u16x4 o;
  o[0] = f2bf(v.x); o[1] = f2bf(v.y); o[2] = f2bf(v.z); o[3] = f2bf(v.w);
  *(u16x4*)(dst + off) = o;
}

// ================= fused QKV GEMM: 256x256 tile, 8-phase, counted vmcnt ====
template <int N0>
__device__ __forceinline__ void mfma16(f32x4 (&acc)[8][4], B8 (&af)[8], B8& b0,
                                       B8& b1) {
  __builtin_amdgcn_s_setprio(1);
#pragma unroll
  for (int m = 0; m < 8; ++m) {
    acc[m][N0] = MFMA_BF16(af[m].b, b0.b, acc[m][N0]);
    acc[m][N0 + 1] = MFMA_BF16(af[m].b, b1.b, acc[m][N0 + 1]);
  }
  __builtin_amdgcn_s_setprio(0);
}

__global__ __launch_bounds__(512, 2) void gemm_qkv256(
    const u16* __restrict__ Xb, const u16* __restrict__ Wb,
    u16* __restrict__ Qb, u16* __restrict__ Kb, u16* __restrict__ Vt) {
  __shared__ __align__(16) u16 Al[2][2][256 * 32];
  __shared__ __align__(16) u16 Bl[2][2][256 * 32];

  int tid = threadIdx.x, lane = tid & 63, w = tid >> 6;
  int wr = w >> 2, wc = w & 3;
  int l16 = lane & 15, lg = lane >> 4;

  int bid = blockIdx.x;
  int swz = (bid & 7) * 24 + (bid >> 3);
  int bm = swz / 12, bn = swz % 12;

  const u16* Ag = Xb + (size_t)bm * 256 * 1024;
  const u16* Bg = Wb + (size_t)bn * 256 * 1024;

  int srow = w * 16 + (lane >> 2);
  int scol = lane & 3;

  auto stA = [&](int buf, int kh, int kt) {
#pragma unroll
    for (int p2 = 0; p2 < 2; ++p2) {
      int r = p2 * 128 + srow;
      int sl = scol ^ ((r >> 1) & 3);
      gl2lds16(Ag + (size_t)r * 1024 + kt * 64 + kh * 32 + sl * 8,
               (char*)&Al[buf][kh][0] + (size_t)(p2 * 128 + w * 16) * 64);
    }
  };
  auto stB = [&](int buf, int kh, int kt) {
#pragma unroll
    for (int p2 = 0; p2 < 2; ++p2) {
      int r = p2 * 128 + srow;
      int sl = scol ^ ((r >> 1) & 3);
      gl2lds16(Bg + (size_t)r * 1024 + kt * 64 + kh * 32 + sl * 8,
               (char*)&Bl[buf][kh][0] + (size_t)(p2 * 128 + w * 16) * 64);
    }
  };
  auto ldA = [&](int buf, int kk, B8 (&af)[8]) {
#pragma unroll
    for (int m = 0; m < 8; ++m) {
      int r = wr * 128 + m * 16 + l16;
      af[m].u = *(const u16x8*)((const char*)&Al[buf][kk][0] + r * 64 +
                                ((lg ^ ((r >> 1) & 3)) << 4));
    }
  };
  auto ldB = [&](int buf, int kk, int nf, B8& bf) {
    int r = wc * 64 + nf * 16 + l16;
    bf.u = *(const u16x8*)((const char*)&Bl[buf][kk][0] + r * 64 +
                           ((lg ^ ((r >> 1) & 3)) << 4));
  };

  f32x4 acc[8][4] = {};

  stA(0, 0, 0); stB(0, 0, 0);
  stA(0, 1, 0); stB(0, 1, 0);
  stA(1, 0, 1); stB(1, 0, 1);
  asm volatile("s_waitcnt vmcnt(8)" ::: "memory");
  __builtin_amdgcn_s_barrier();

  B8 af[8], b0, b1;
  for (int I = 0; I < 8; ++I) {
    int p = 2 * I;
    bool last = (I == 7);
    stA(1, 1, p + 1);
    ldA(0, 0, af); ldB(0, 0, 0, b0); ldB(0, 0, 1, b1);
    mfma16<0>(acc, af, b0, b1);
    stB(1, 1, p + 1);
    ldB(0, 0, 2, b0); ldB(0, 0, 3, b1);
    mfma16<2>(acc, af, b0, b1);
    if (last) asm volatile("s_waitcnt vmcnt(0)" ::: "memory");
    else      asm volatile("s_waitcnt vmcnt(8)" ::: "memory");
    __builtin_amdgcn_s_barrier();
    if (!last) stA(0, 0, p + 2);
    ldA(0, 1, af); ldB(0, 1, 0, b0); ldB(0, 1, 1, b1);
    mfma16<0>(acc, af, b0, b1);
    if (!last) stB(0, 0, p + 2);
    ldB(0, 1, 2, b0); ldB(0, 1, 3, b1);
    mfma16<2>(acc, af, b0, b1);
    if (last) asm volatile("s_waitcnt vmcnt(0)" ::: "memory");
    else      asm volatile("s_waitcnt vmcnt(8)" ::: "memory");
    __builtin_amdgcn_s_barrier();
    if (!last) stA(0, 1, p + 2);
    ldA(1, 0, af); ldB(1, 0, 0, b0); ldB(1, 0, 1, b1);
    mfma16<0>(acc, af, b0, b1);
    if (!last) stB(0, 1, p + 2);
    ldB(1, 0, 2, b0); ldB(1, 0, 3, b1);
    mfma16<2>(acc, af, b0, b1);
    if (last) asm volatile("s_waitcnt vmcnt(0)" ::: "memory");
    else      asm volatile("s_waitcnt vmcnt(8)" ::: "memory");
    __builtin_amdgcn_s_barrier();
    if (!last) stA(1, 0, p + 3);
    ldA(1, 1, af); ldB(1, 1, 0, b0); ldB(1, 1, 1, b1);
    mfma16<0>(acc, af, b0, b1);
    if (!last) stB(1, 0, p + 3);
    ldB(1, 1, 2, b0); ldB(1, 1, 3, b1);
    mfma16<2>(acc, af, b0, b1);
    if (!last) {
      asm volatile("s_waitcnt vmcnt(8)" ::: "memory");
      __builtin_amdgcn_s_barrier();
    }
  }

  const float QSCALE = 0.18033688011112042f;  // 0.125 * log2(e)
#pragma unroll
  for (int m = 0; m < 8; ++m)
#pragma unroll
    for (int nf = 0; nf < 4; ++nf) {
      int colg = bn * 256 + wc * 64 + nf * 16 + l16;
      int rowg = bm * 256 + wr * 128 + m * 16 + lg * 4;
      if (bn < 4) {
#pragma unroll
        for (int j = 0; j < 4; ++j)
          Qb[(size_t)(rowg + j) * 1024 + colg] = f2bf(acc[m][nf][j] * QSCALE);
      } else if (bn < 8) {
#pragma unroll
        for (int j = 0; j < 4; ++j)
          Kb[(size_t)(rowg + j) * 1024 + (colg - 1024)] = f2bf(acc[m][nf][j]);
      } else {
        int cv = colg - 2048;
        int hh = cv >> 6, d = cv & 63;
        int bb = rowg >> 11, s0 = rowg & 2047;
        u16x4 pk;
#pragma unroll
        for (int j = 0; j < 4; ++j) pk[j] = f2bf(acc[m][nf][j]);
        *(u16x4*)(Vt + ((size_t)(bb * 16 + hh) * 64 + d) * 2048 + s0) = pk;
      }
    }
}

// ---------------- proj GEMM (128x128, double-buffered prefetch) -----------
__global__ __launch_bounds__(256) void gemm_proj_kernel(
    const u16* __restrict__ Y1, const u16* __restrict__ Wpb,
    float* __restrict__ out, const float* __restrict__ bias) {
  __shared__ __align__(16) u16 Asm[2][128 * 64];
  __shared__ __align__(16) u16 Bsm[2][128 * 64];

  const int Kd = 1024, N = 1024;
  int bm = blockIdx.y, bn = blockIdx.x;
  int tid = threadIdx.x;
  int lane = tid & 63, w = tid >> 6;
  int wr = w >> 1, wc = w & 1;
  int l16 = lane & 15, lg = lane >> 4;

  const u16* Abase = Y1 + (size_t)bm * 128 * Kd;
  const u16* Bbase = Wpb + (size_t)bn * 128 * Kd;

  int r0 = tid >> 3;

  auto stage = [&](int buf, int kt) {
#pragma unroll
    for (int i = 0; i < 4; ++i) {
      int r = i * 32 + r0;
      int sl = (tid & 7) ^ (r & 7);
      gl2lds16(Abase + (size_t)r * Kd + kt * 64 + sl * 8,
               &Asm[buf][i * 2048 + w * 512]);
      gl2lds16(Bbase + (size_t)r * Kd + kt * 64 + sl * 8,
               &Bsm[buf][i * 2048 + w * 512]);
    }
  };

  f32x4 acc[4][4] = {};
  stage(0, 0);
  int buf = 0;

  for (int kt = 0; kt < 16; ++kt) {
    asm volatile("s_waitcnt vmcnt(0)" ::: "memory");
    __syncthreads();
    if (kt + 1 < 16) stage(buf ^ 1, kt + 1);

    B8 af[4][2], bfr[4][2];
#pragma unroll
    for (int mi = 0; mi < 4; ++mi)
#pragma unroll
      for (int kk = 0; kk < 2; ++kk) {
        int r = wr * 64 + mi * 16 + l16;
        int s = kk * 4 + lg;
        af[mi][kk].u = *(const u16x8*)((const char*)&Asm[buf][0] + r * 128 +
                                       ((s ^ (r & 7)) << 4));
      }
#pragma unroll
    for (int ni = 0; ni < 4; ++ni)
#pragma unroll
      for (int kk = 0; kk < 2; ++kk) {
        int r = wc * 64 + ni * 16 + l16;
        int s = kk * 4 + lg;
        bfr[ni][kk].u = *(const u16x8*)((const char*)&Bsm[buf][0] + r * 128 +
                                        ((s ^ (r & 7)) << 4));
      }
    __builtin_amdgcn_s_setprio(1);
#pragma unroll
    for (int mi = 0; mi < 4; ++mi)
#pragma unroll
      for (int ni = 0; ni < 4; ++ni) {
        acc[mi][ni] = MFMA_BF16(af[mi][0].b, bfr[ni][0].b, acc[mi][ni]);
        acc[mi][ni] = MFMA_BF16(af[mi][1].b, bfr[ni][1].b, acc[mi][ni]);
      }
    __builtin_amdgcn_s_setprio(0);
    buf ^= 1;
  }

#pragma unroll
  for (int mi = 0; mi < 4; ++mi)
#pragma unroll
    for (int ni = 0; ni < 4; ++ni) {
      int col = bn * 128 + wc * 64 + ni * 16 + l16;
#pragma unroll
      for (int j = 0; j < 4; ++j) {
        int row = bm * 128 + wr * 64 + mi * 16 + lg * 4 + j;
        out[(size_t)row * N + col] = acc[mi][ni][j] + bias[col];
      }
    }
}

// ---------------- flash attention (causal), V direct from cache -----------
// Round-7 structure (16 q-rows/wave, 1024 blocks, balanced qt) but:
//  - V is NOT staged in LDS: PV B-fragments are 16B-contiguous reads of
//    Vt[b][h][d][S], loaded straight from L1/L2 at PV time.
//  - bh swizzle: the 4 blocks resident on one CU share (b,h) -> V tile is
//    L1-hot; each XCD touches only 4 heads (KV set 2MB < 4MB L2).
__global__ __launch_bounds__(256, 4) void attn_kernel(const u16* __restrict__ Q,
                                                      const u16* __restrict__ K,
                                                      const u16* __restrict__ Vt,
                                                      u16* __restrict__ Y) {
  __shared__ __align__(16) u16 Kl[2][64 * 64];
  __shared__ __align__(16) u16 Pl[4][16 * 64];

  const int E = 1024, S = 2048;
  int tid = threadIdx.x;
  int lane = tid & 63, w = tid >> 6;
  int l16 = lane & 15, lg = lane >> 4;
  int h7 = l16 & 7;

  int bid = blockIdx.x;
  // bh swizzle: same-CU blocks share bh; each XCD owns 4 heads
  int bh = (bid & 7) * 4 + ((bid >> 3) & 3);
  int u = bid >> 5;  // 0..31
  int g = u & 7, kq = u >> 3;
  int qt = (kq == 0) ? 31 - g : (kq == 1) ? 16 + g : (kq == 2) ? 15 - g : g;
  int b = bh >> 4, h = bh & 15;

  const u16* Qb = Q + (size_t)b * S * E + (size_t)h * 64;
  const u16* Kb = K + (size_t)b * S * E + (size_t)h * 64;
  const u16* Vb = Vt + (size_t)bh * 64 * 2048;

  // ---- K staging offsets / pointers (loop-invariant)
  int r0 = tid >> 3;
  int s0 = (tid & 7) ^ (r0 & 7);
  size_t koff = (size_t)r0 * 1024 + s0 * 8;
  const u16* kpA = Kb;              // rows 0..31 of current tile
  const u16* kpB = Kb + 32 * 1024;  // rows 32..63

  // ---- V direct-load pointers: lane reads Vt row d = nb*16+l16,
  //      kv slice lg*8 (+32 for kk=1); advance 64 kv per tile.
  const u16* vg0 = Vb + (size_t)(0 * 16 + l16) * 2048 + lg * 8;
  const u16* vg1 = Vb + (size_t)(1 * 16 + l16) * 2048 + lg * 8;
  const u16* vg2 = Vb + (size_t)(2 * 16 + l16) * 2048 + lg * 8;
  const u16* vg3 = Vb + (size_t)(3 * 16 + l16) * 2048 + lg * 8;

  // ---- LDS bases (loop-invariant)
  const char* kbase0 = (const char*)&Kl[0][0] + l16 * 128 + ((lg ^ h7) << 4);
  const char* kbase1 = (const char*)&Kl[0][0] + l16 * 128 + (((4 + lg) ^ h7) << 4);
  char* pw0 = (char*)&Pl[w][0] + l16 * 128 + (((0 * 2 + (lg >> 1)) ^ h7) << 4) + (lg & 1) * 8;
  char* pw1 = (char*)&Pl[w][0] + l16 * 128 + (((1 * 2 + (lg >> 1)) ^ h7) << 4) + (lg & 1) * 8;
  char* pw2 = (char*)&Pl[w][0] + l16 * 128 + (((2 * 2 + (lg >> 1)) ^ h7) << 4) + (lg & 1) * 8;
  char* pw3 = (char*)&Pl[w][0] + l16 * 128 + (((3 * 2 + (lg >> 1)) ^ h7) << 4) + (lg & 1) * 8;
  const char* pr0 = (const char*)&Pl[w][0] + l16 * 128 + ((lg ^ h7) << 4);
  const char* pr1 = (const char*)&Pl[w][0] + l16 * 128 + (((4 + lg) ^ h7) << 4);

  B8 qa[2];
#pragma unroll
  for (int kk = 0; kk < 2; ++kk)
    qa[kk].u = *(const u16x8*)(Qb + (size_t)(qt * 64 + w * 16 + l16) * E + kk * 32 + lg * 8);

  f32x4 o[4] = {};
  float lrun = 0.f;
  int qrow = w * 16 + l16;

  // prologue: stage K tile 0 into buf 0
  gl2lds16(kpA + koff, &Kl[0][w * 512]);
  gl2lds16(kpB + koff, &Kl[0][2048 + w * 512]);
  kpA += 65536; kpB += 65536;

#define ATTN_ITER(BF, DOMASK, DOSTAGE)                                         \
  do {                                                                         \
    asm volatile("s_waitcnt vmcnt(0)" ::: "memory");                           \
    __syncthreads();                                                           \
    if (DOSTAGE) {                                                             \
      gl2lds16(kpA + koff, &Kl[(BF) ^ 1][w * 512]);                            \
      gl2lds16(kpB + koff, &Kl[(BF) ^ 1][2048 + w * 512]);                     \
      kpA += 65536; kpB += 65536;                                              \
    }                                                                          \
    f32x4 sa[4] = {};                                                          \
    __builtin_amdgcn_s_setprio(1);                                             \
    _Pragma("unroll") for (int nb = 0; nb < 4; ++nb) {                         \
      B8 kf0, kf1;                                                             \
      kf0.u = *(const u16x8*)(kbase0 + (BF)*8192 + nb * 2048);                 \
      kf1.u = *(const u16x8*)(kbase1 + (BF)*8192 + nb * 2048);                 \
      sa[nb] = MFMA_BF16(kf0.b, qa[0].b, sa[nb]);                              \
      sa[nb] = MFMA_BF16(kf1.b, qa[1].b, sa[nb]);                              \
    }                                                                          \
    __builtin_amdgcn_s_setprio(0);                                             \
    B8 vf[4][2];                                                               \
    vf[0][0].u = *(const u16x8*)(vg0);                                         \
    vf[0][1].u = *(const u16x8*)(vg0 + 32);                                    \
    vf[1][0].u = *(const u16x8*)(vg1);                                         \
    vf[1][1].u = *(const u16x8*)(vg1 + 32);                                    \
    vf[2][0].u = *(const u16x8*)(vg2);                                         \
    vf[2][1].u = *(const u16x8*)(vg2 + 32);                                    \
    vf[3][0].u = *(const u16x8*)(vg3);                                         \
    vf[3][1].u = *(const u16x8*)(vg3 + 32);                                    \
    vg0 += 64; vg1 += 64; vg2 += 64; vg3 += 64;                                \
    float p[16];                                                               \
    _Pragma("unroll") for (int nb = 0; nb < 4; ++nb)                           \
        _Pragma("unroll") for (int j = 0; j < 4; ++j) {                        \
      float pe = __builtin_amdgcn_exp2f(sa[nb][j]);                            \
      if (DOMASK) {                                                            \
        int kv = nb * 16 + lg * 4 + j;                                         \
        if (kv > qrow) pe = 0.f;                                               \
      }                                                                        \
      p[nb * 4 + j] = pe;                                                      \
    }                                                                          \
    {                                                                          \
      union { u16x4 v; unsigned uu[2]; } pk;                                   \
      pk.uu[0] = cvt_pk_bf16(p[0], p[1]);                                      \
      pk.uu[1] = cvt_pk_bf16(p[2], p[3]);                                      \
      *(u16x4*)pw0 = pk.v;                                                     \
      pk.uu[0] = cvt_pk_bf16(p[4], p[5]);                                      \
      pk.uu[1] = cvt_pk_bf16(p[6], p[7]);                                      \
      *(u16x4*)pw1 = pk.v;                                                     \
      pk.uu[0] = cvt_pk_bf16(p[8], p[9]);                                      \
      pk.uu[1] = cvt_pk_bf16(p[10], p[11]);                                    \
      *(u16x4*)pw2 = pk.v;                                                     \
      pk.uu[0] = cvt_pk_bf16(p[12], p[13]);                                    \
      pk.uu[1] = cvt_pk_bf16(p[14], p[15]);                                    \
      *(u16x4*)pw3 = pk.v;                                                     \
    }                                                                          \
    lrun += ((p[0] + p[1]) + (p[2] + p[3])) + ((p[4] + p[5]) + (p[6] + p[7])) +\
            ((p[8] + p[9]) + (p[10] + p[11])) +                                \
            ((p[12] + p[13]) + (p[14] + p[15]));                               \
    B8 pa0, pa1;                                                               \
    pa0.u = *(const u16x8*)pr0;                                                \
    pa1.u = *(const u16x8*)pr1;                                                \
    __builtin_amdgcn_s_setprio(1);                                             \
    _Pragma("unroll") for (int nb = 0; nb < 4; ++nb) {                         \
      o[nb] = MFMA_BF16(pa0.b, vf[nb][0].b, o[nb]);                            \
      o[nb] = MFMA_BF16(pa1.b, vf[nb][1].b, o[nb]);                            \
    }                                                                          \
    __builtin_amdgcn_s_setprio(0);                                             \
  } while (0)

  int U = qt;  // tiles 0..U-1 unmasked, tile U masked (diagonal)
  int i = 0;
  for (; i + 2 <= U; i += 2) {
    ATTN_ITER(0, false, true);
    ATTN_ITER(1, false, true);
  }
  if (U & 1) {
    ATTN_ITER(0, false, true);   // index U-1 (even) -> buf 0, stages tile U
    ATTN_ITER(1, true, false);   // masked tile U in buf 1
  } else {
    ATTN_ITER(0, true, false);   // masked tile U in buf 0
  }
#undef ATTN_ITER

  // epilogue: reduce partial sums across the 4 lg-lanes of each q-row
  lrun += __shfl_xor(lrun, 16);
  lrun += __shfl_xor(lrun, 32);
  float inv[4];
#pragma unroll
  for (int j = 0; j < 4; ++j) {
    float lj = __shfl(lrun, (lane & 48) | (lg * 4 + j));
    inv[j] = 1.0f / lj;
  }
#pragma unroll
  for (int nb = 0; nb < 4; ++nb)
#pragma unroll
    for (int j = 0; j < 4; ++j) {
      int row = qt * 64 + w * 16 + lg * 4 + j;
      int col = h * 64 + nb * 16 + l16;
      Y[((size_t)b * S + row) * E + col] = f2bf(o[nb][j] * inv[j]);
    }
}

extern "C" void kernel_launch(void* const* d_in, const int* in_sizes, int n_in,
                              void* d_out, int out_size, void* d_ws,
                              size_t ws_size, hipStream_t stream) {
  const float* X = (const float*)d_in[0];
  const float* Wq = (const float*)d_in[1];
  const float* Wk = (const float*)d_in[2];
  const float* Wv = (const float*)d_in[3];
  const float* Wp = (const float*)d_in[4];
  const float* bp = (const float*)d_in[5];
  float* out = (float*)d_out;

  char* ws = (char*)d_ws;
  const size_t MB = 1ull << 20;
  u16* Xb = (u16*)(ws + 0 * MB);
  u16* Wqb = (u16*)(ws + 8 * MB);   // Wq,Wk,Wv contiguous -> fused [3072][1024]
  u16* Wkb = (u16*)(ws + 10 * MB);
  u16* Wvb = (u16*)(ws + 12 * MB);
  u16* Wpb = (u16*)(ws + 14 * MB);
  u16* Qb = (u16*)(ws + 16 * MB);
  u16* Kb = (u16*)(ws + 24 * MB);
  u16* VtB = (u16*)(ws + 32 * MB);  // Vt[b][h][64][2048]
  u16* Y1 = (u16*)(ws + 40 * MB);

  cast5_kernel<<<8192, 256, 0, stream>>>(X, Wq, Wk, Wv, Wp, Xb, Wqb, Wkb, Wvb, Wpb);
  gemm_qkv256<<<192, 512, 0, stream>>>(Xb, Wqb, Qb, Kb, VtB);
  attn_kernel<<<1024, 256, 0, stream>>>(Qb, Kb, VtB, Y1);
  gemm_proj_kernel<<<dim3(8, 32), 256, 0, stream>>>(Y1, Wpb, out, bp);
}

// Round 11
// 104.777 us; speedup vs baseline: 1.4435x; 1.4435x over previous
//
#include <hip/hip_runtime.h>

typedef unsigned short u16;
typedef __bf16 bf16x8 __attribute__((ext_vector_type(8)));
typedef float f32x4 __attribute__((ext_vector_type(4)));
typedef unsigned short u16x8 __attribute__((ext_vector_type(8)));
typedef unsigned short u16x4 __attribute__((ext_vector_type(4)));

union B8 { u16x8 u; bf16x8 b; };

#define MFMA_BF16(a, b, c) __builtin_amdgcn_mfma_f32_16x16x32_bf16((a), (b), (c), 0, 0, 0)

__device__ __forceinline__ u16 f2bf(float f) {
  unsigned x = __float_as_uint(f);
  unsigned r = x + 0x7fffu + ((x >> 16) & 1u);
  return (u16)(r >> 16);
}

__device__ __forceinline__ unsigned cvt_pk_bf16(float lo, float hi) {
  unsigned r;
  asm("v_cvt_pk_bf16_f32 %0, %1, %2" : "=v"(r) : "v"(lo), "v"(hi));
  return r;
}

__device__ __forceinline__ void gl2lds16(const void* g, void* l) {
  __builtin_amdgcn_global_load_lds(
      (const __attribute__((address_space(1))) void*)g,
      (__attribute__((address_space(3))) void*)l, 16, 0, 0);
}

// ---------------- cast f32 -> bf16 (X, Wq, Wk, Wv, Wp) ----------------
__global__ __launch_bounds__(256) void cast5_kernel(
    const float* __restrict__ X, const float* __restrict__ Wq,
    const float* __restrict__ Wk, const float* __restrict__ Wv,
    const float* __restrict__ Wp, u16* __restrict__ Xb, u16* __restrict__ Wqb,
    u16* __restrict__ Wkb, u16* __restrict__ Wvb, u16* __restrict__ Wpb) {
  size_t i = ((size_t)blockIdx.x * 256 + threadIdx.x) * 4;
  const float* src;
  u16* dst;
  size_t off;
  if (i < 4194304) {
    src = X; dst = Xb; off = i;
  } else if (i < 5242880) {
    src = Wq; dst = Wqb; off = i - 4194304;
  } else if (i < 6291456) {
    src = Wk; dst = Wkb; off = i - 5242880;
  } else if (i < 7340032) {
    src = Wv; dst = Wvb; off = i - 6291456;
  } else {
    src = Wp; dst = Wpb; off = i - 7340032;
  }
  float4 v = *(const float4*)(src + off);
  u16x4 o;
  o[0] = f2bf(v.x); o[1] = f2bf(v.y); o[2] = f2bf(v.z); o[3] = f2bf(v.w);
  *(u16x4*)(dst + off) = o;
}

// ===== fused QKV GEMM: 256x192 tile, 8-phase, counted vmcnt, 256 blocks ====
// C[4096,3072] = Xb * Wb^T.  Column region per fragment: <1024 Q (scaled),
// <2048 K, else V transposed (Vt[b][h][d][S]).  8 waves (2Mx4N), wave tile
// 128x48 (acc[8][3]).  B staging = 1.5 passes: waves 0-3 issue 2 loads/stB,
// waves 4-7 issue 1 -> per-wave counted vmcnt(8)/(6).
template <int MLO>
__device__ __forceinline__ void mfma12(f32x4 (&acc)[8][3], B8 (&af)[8], B8& b0,
                                       B8& b1, B8& b2) {
  __builtin_amdgcn_s_setprio(1);
#pragma unroll
  for (int m = MLO; m < MLO + 4; ++m) {
    acc[m][0] = MFMA_BF16(af[m].b, b0.b, acc[m][0]);
    acc[m][1] = MFMA_BF16(af[m].b, b1.b, acc[m][1]);
    acc[m][2] = MFMA_BF16(af[m].b, b2.b, acc[m][2]);
  }
  __builtin_amdgcn_s_setprio(0);
}

__global__ __launch_bounds__(512, 1) void gemm_qkv192(
    const u16* __restrict__ Xb, const u16* __restrict__ Wb,
    u16* __restrict__ Qb, u16* __restrict__ Kb, u16* __restrict__ Vt) {
  __shared__ __align__(16) u16 Al[2][2][256 * 32];
  __shared__ __align__(16) u16 Bl[2][2][192 * 32];

  int tid = threadIdx.x, lane = tid & 63, w = tid >> 6;
  int wr = w >> 2, wc = w & 3;
  int l16 = lane & 15, lg = lane >> 4;

  // XCD swizzle: 256 % 8 == 0; XCD x gets 2 bm panels x all 16 bn
  int bid = blockIdx.x;
  int swz = (bid & 7) * 32 + (bid >> 3);
  int bm = swz >> 4, bn = swz & 15;

  const u16* Ag = Xb + (size_t)bm * 256 * 1024;
  const u16* Bg = Wb + (size_t)bn * 192 * 1024;

  int lr = lane >> 2;   // 0..15: row within 16-row wave chunk
  int lc = lane & 3;    // 16B slot within 64B row

  auto stA = [&](int buf, int kh, int kt) {
#pragma unroll
    for (int p2 = 0; p2 < 2; ++p2) {
      int r = p2 * 128 + w * 16 + lr;
      int sl = lc ^ ((r >> 1) & 3);
      gl2lds16(Ag + (size_t)r * 1024 + kt * 64 + kh * 32 + sl * 8,
               (char*)&Al[buf][kh][0] + (size_t)(p2 * 128 + w * 16) * 64);
    }
  };
  auto stB = [&](int buf, int kh, int kt) {
    {
      int r = w * 16 + lr;
      int sl = lc ^ ((r >> 1) & 3);
      gl2lds16(Bg + (size_t)r * 1024 + kt * 64 + kh * 32 + sl * 8,
               (char*)&Bl[buf][kh][0] + (size_t)(w * 16) * 64);
    }
    if (w < 4) {
      int r = 128 + w * 16 + lr;
      int sl = lc ^ ((r >> 1) & 3);
      gl2lds16(Bg + (size_t)r * 1024 + kt * 64 + kh * 32 + sl * 8,
               (char*)&Bl[buf][kh][0] + (size_t)(128 + w * 16) * 64);
    }
  };
  auto ldA = [&](int buf, int kk, B8 (&af)[8]) {
#pragma unroll
    for (int m = 0; m < 8; ++m) {
      int r = wr * 128 + m * 16 + l16;
      af[m].u = *(const u16x8*)((const char*)&Al[buf][kk][0] + r * 64 +
                                ((lg ^ ((r >> 1) & 3)) << 4));
    }
  };
  auto ldB = [&](int buf, int kk, int nf, B8& bf) {
    int r = wc * 48 + nf * 16 + l16;
    bf.u = *(const u16x8*)((const char*)&Bl[buf][kk][0] + r * 64 +
                           ((lg ^ ((r >> 1) & 3)) << 4));
  };

#define WAITC(LAST)                                                            \
  do {                                                                         \
    if (LAST) asm volatile("s_waitcnt vmcnt(0)" ::: "memory");                 \
    else if (w < 4) asm volatile("s_waitcnt vmcnt(8)" ::: "memory");           \
    else asm volatile("s_waitcnt vmcnt(6)" ::: "memory");                      \
  } while (0)

  f32x4 acc[8][3] = {};

  // prologue: tile0 (k0,k1) -> buf0; tile1.k0 -> buf1
  stA(0, 0, 0); stB(0, 0, 0);
  stA(0, 1, 0); stB(0, 1, 0);
  stA(1, 0, 1); stB(1, 0, 1);
  WAITC(false);
  __builtin_amdgcn_s_barrier();

  B8 af[8], b0, b1, b2;
  for (int I = 0; I < 8; ++I) {
    int p = 2 * I;
    bool last = (I == 7);
    // ph1: compute tile p kk0 m0..3; stage (p+1).k1 A
    stA(1, 1, p + 1);
    ldA(0, 0, af); ldB(0, 0, 0, b0); ldB(0, 0, 1, b1); ldB(0, 0, 2, b2);
    mfma12<0>(acc, af, b0, b1, b2);
    // ph2: m4..7; stage (p+1).k1 B
    stB(1, 1, p + 1);
    mfma12<4>(acc, af, b0, b1, b2);
    WAITC(last);
    __builtin_amdgcn_s_barrier();
    // ph3: tile p kk1 m0..3; stage (p+2).k0 A
    if (!last) stA(0, 0, p + 2);
    ldA(0, 1, af); ldB(0, 1, 0, b0); ldB(0, 1, 1, b1); ldB(0, 1, 2, b2);
    mfma12<0>(acc, af, b0, b1, b2);
    // ph4: m4..7; stage (p+2).k0 B
    if (!last) stB(0, 0, p + 2);
    mfma12<4>(acc, af, b0, b1, b2);
    WAITC(last);
    __builtin_amdgcn_s_barrier();
    // ph5: tile p+1 kk0 m0..3; stage (p+2).k1 A
    if (!last) stA(0, 1, p + 2);
    ldA(1, 0, af); ldB(1, 0, 0, b0); ldB(1, 0, 1, b1); ldB(1, 0, 2, b2);
    mfma12<0>(acc, af, b0, b1, b2);
    // ph6: m4..7; stage (p+2).k1 B
    if (!last) stB(0, 1, p + 2);
    mfma12<4>(acc, af, b0, b1, b2);
    WAITC(last);
    __builtin_amdgcn_s_barrier();
    // ph7: tile p+1 kk1 m0..3; stage (p+3).k0 A
    if (!last) stA(1, 0, p + 3);
    ldA(1, 1, af); ldB(1, 1, 0, b0); ldB(1, 1, 1, b1); ldB(1, 1, 2, b2);
    mfma12<0>(acc, af, b0, b1, b2);
    // ph8: m4..7; stage (p+3).k0 B
    if (!last) stB(1, 0, p + 3);
    mfma12<4>(acc, af, b0, b1, b2);
    if (!last) {
      WAITC(false);
      __builtin_amdgcn_s_barrier();
    }
  }
#undef WAITC

  const float QSCALE = 0.18033688011112042f;  // 0.125 * log2(e)
#pragma unroll
  for (int m = 0; m < 8; ++m)
#pragma unroll
    for (int nf = 0; nf < 3; ++nf) {
      int colg = bn * 192 + wc * 48 + nf * 16 + l16;
      int rowg = bm * 256 + wr * 128 + m * 16 + lg * 4;
      if (colg < 1024) {
#pragma unroll
        for (int j = 0; j < 4; ++j)
          Qb[(size_t)(rowg + j) * 1024 + colg] = f2bf(acc[m][nf][j] * QSCALE);
      } else if (colg < 2048) {
#pragma unroll
        for (int j = 0; j < 4; ++j)
          Kb[(size_t)(rowg + j) * 1024 + (colg - 1024)] = f2bf(acc[m][nf][j]);
      } else {
        int cv = colg - 2048;
        int hh = cv >> 6, d = cv & 63;
        int bb = rowg >> 11, s0r = rowg & 2047;
        u16x4 pk;
#pragma unroll
        for (int j = 0; j < 4; ++j) pk[j] = f2bf(acc[m][nf][j]);
        *(u16x4*)(Vt + ((size_t)(bb * 16 + hh) * 64 + d) * 2048 + s0r) = pk;
      }
    }
}

// ---------------- proj GEMM (128x128, double-buffered prefetch) -----------
__global__ __launch_bounds__(256) void gemm_proj_kernel(
    const u16* __restrict__ Y1, const u16* __restrict__ Wpb,
    float* __restrict__ out, const float* __restrict__ bias) {
  __shared__ __align__(16) u16 Asm[2][128 * 64];
  __shared__ __align__(16) u16 Bsm[2][128 * 64];

  const int Kd = 1024, N = 1024;
  int bm = blockIdx.y, bn = blockIdx.x;
  int tid = threadIdx.x;
  int lane = tid & 63, w = tid >> 6;
  int wr = w >> 1, wc = w & 1;
  int l16 = lane & 15, lg = lane >> 4;

  const u16* Abase = Y1 + (size_t)bm * 128 * Kd;
  const u16* Bbase = Wpb + (size_t)bn * 128 * Kd;

  int r0 = tid >> 3;

  auto stage = [&](int buf, int kt) {
#pragma unroll
    for (int i = 0; i < 4; ++i) {
      int r = i * 32 + r0;
      int sl = (tid & 7) ^ (r & 7);
      gl2lds16(Abase + (size_t)r * Kd + kt * 64 + sl * 8,
               &Asm[buf][i * 2048 + w * 512]);
      gl2lds16(Bbase + (size_t)r * Kd + kt * 64 + sl * 8,
               &Bsm[buf][i * 2048 + w * 512]);
    }
  };

  f32x4 acc[4][4] = {};
  stage(0, 0);
  int buf = 0;

  for (int kt = 0; kt < 16; ++kt) {
    asm volatile("s_waitcnt vmcnt(0)" ::: "memory");
    __syncthreads();
    if (kt + 1 < 16) stage(buf ^ 1, kt + 1);

    B8 af[4][2], bfr[4][2];
#pragma unroll
    for (int mi = 0; mi < 4; ++mi)
#pragma unroll
      for (int kk = 0; kk < 2; ++kk) {
        int r = wr * 64 + mi * 16 + l16;
        int s = kk * 4 + lg;
        af[mi][kk].u = *(const u16x8*)((const char*)&Asm[buf][0] + r * 128 +
                                       ((s ^ (r & 7)) << 4));
      }
#pragma unroll
    for (int ni = 0; ni < 4; ++ni)
#pragma unroll
      for (int kk = 0; kk < 2; ++kk) {
        int r = wc * 64 + ni * 16 + l16;
        int s = kk * 4 + lg;
        bfr[ni][kk].u = *(const u16x8*)((const char*)&Bsm[buf][0] + r * 128 +
                                        ((s ^ (r & 7)) << 4));
      }
    __builtin_amdgcn_s_setprio(1);
#pragma unroll
    for (int mi = 0; mi < 4; ++mi)
#pragma unroll
      for (int ni = 0; ni < 4; ++ni) {
        acc[mi][ni] = MFMA_BF16(af[mi][0].b, bfr[ni][0].b, acc[mi][ni]);
        acc[mi][ni] = MFMA_BF16(af[mi][1].b, bfr[ni][1].b, acc[mi][ni]);
      }
    __builtin_amdgcn_s_setprio(0);
    buf ^= 1;
  }

#pragma unroll
  for (int mi = 0; mi < 4; ++mi)
#pragma unroll
    for (int ni = 0; ni < 4; ++ni) {
      int col = bn * 128 + wc * 64 + ni * 16 + l16;
#pragma unroll
      for (int j = 0; j < 4; ++j) {
        int row = bm * 128 + wr * 64 + mi * 16 + lg * 4 + j;
        out[(size_t)row * N + col] = acc[mi][ni][j] + bias[col];
      }
    }
}

// ---------------- flash attention (causal), fixed-origin softmax ----------
// Round-7 measured-best structure: 16 q-rows/wave, 64-row q-tiles,
// 1024 blocks (4/CU), balanced qt permutation, unroll-by-2 compile-time buf,
// K and V staged via swizzled global_load_lds (shared + prefetched).
__global__ __launch_bounds__(256, 4) void attn_kernel(const u16* __restrict__ Q,
                                                      const u16* __restrict__ K,
                                                      const u16* __restrict__ Vt,
                                                      u16* __restrict__ Y) {
  __shared__ __align__(16) u16 Kl[2][64 * 64];
  __shared__ __align__(16) u16 Vl[2][64 * 64];
  __shared__ __align__(16) u16 Pl[4][16 * 64];

  const int E = 1024, S = 2048;
  int tid = threadIdx.x;
  int lane = tid & 63, w = tid >> 6;
  int l16 = lane & 15, lg = lane >> 4;
  int h7 = l16 & 7;

  int bid = blockIdx.x;
  int bh = bid & 31;
  int u = bid >> 5;  // 0..31
  int g = u & 7, kq = u >> 3;
  // balance-perfect bijection: per-CU 4-block iteration totals are equal
  int qt = (kq == 0) ? 31 - g : (kq == 1) ? 16 + g : (kq == 2) ? 15 - g : g;
  int b = bh >> 4, h = bh & 15;

  const u16* Qb = Q + (size_t)b * S * E + (size_t)h * 64;
  const u16* Kb = K + (size_t)b * S * E + (size_t)h * 64;
  const u16* Vb = Vt + (size_t)bh * 64 * 2048;

  // ---- loop-invariant staging offsets / pointers
  int r0 = tid >> 3;
  int s0 = (tid & 7) ^ (r0 & 7);
  size_t koff = (size_t)r0 * 1024 + s0 * 8;
  size_t voff = (size_t)r0 * 2048 + s0 * 8;
  const u16* kpA = Kb;              // rows 0..31 of current tile
  const u16* kpB = Kb + 32 * 1024;  // rows 32..63
  const u16* vpA = Vb;
  const u16* vpB = Vb + 32 * 2048;

  // ---- loop-invariant LDS read/write bases
  const char* kbase0 = (const char*)&Kl[0][0] + l16 * 128 + ((lg ^ h7) << 4);
  const char* kbase1 = (const char*)&Kl[0][0] + l16 * 128 + (((4 + lg) ^ h7) << 4);
  const char* vbase0 = (const char*)&Vl[0][0] + l16 * 128 + ((lg ^ h7) << 4);
  const char* vbase1 = (const char*)&Vl[0][0] + l16 * 128 + (((4 + lg) ^ h7) << 4);
  char* pw0 = (char*)&Pl[w][0] + l16 * 128 + (((0 * 2 + (lg >> 1)) ^ h7) << 4) + (lg & 1) * 8;
  char* pw1 = (char*)&Pl[w][0] + l16 * 128 + (((1 * 2 + (lg >> 1)) ^ h7) << 4) + (lg & 1) * 8;
  char* pw2 = (char*)&Pl[w][0] + l16 * 128 + (((2 * 2 + (lg >> 1)) ^ h7) << 4) + (lg & 1) * 8;
  char* pw3 = (char*)&Pl[w][0] + l16 * 128 + (((3 * 2 + (lg >> 1)) ^ h7) << 4) + (lg & 1) * 8;
  const char* pr0 = (const char*)&Pl[w][0] + l16 * 128 + ((lg ^ h7) << 4);
  const char* pr1 = (const char*)&Pl[w][0] + l16 * 128 + (((4 + lg) ^ h7) << 4);

  B8 qa[2];
#pragma unroll
  for (int kk = 0; kk < 2; ++kk)
    qa[kk].u = *(const u16x8*)(Qb + (size_t)(qt * 64 + w * 16 + l16) * E + kk * 32 + lg * 8);

  f32x4 o[4] = {};
  float lrun = 0.f;
  int qrow = w * 16 + l16;

  // prologue: stage tile 0 into buf 0
  gl2lds16(kpA + koff, &Kl[0][w * 512]);
  gl2lds16(vpA + voff, &Vl[0][w * 512]);
  gl2lds16(kpB + koff, &Kl[0][2048 + w * 512]);
  gl2lds16(vpB + voff, &Vl[0][2048 + w * 512]);
  kpA += 65536; kpB += 65536; vpA += 64; vpB += 64;

#define ATTN_ITER(BF, DOMASK, DOSTAGE)                                         \
  do {                                                                         \
    asm volatile("s_waitcnt vmcnt(0)" ::: "memory");                           \
    __syncthreads();                                                           \
    if (DOSTAGE) {                                                             \
      gl2lds16(kpA + koff, &Kl[(BF) ^ 1][w * 512]);                            \
      gl2lds16(vpA + voff, &Vl[(BF) ^ 1][w * 512]);                            \
      gl2lds16(kpB + koff, &Kl[(BF) ^ 1][2048 + w * 512]);                     \
      gl2lds16(vpB + voff, &Vl[(BF) ^ 1][2048 + w * 512]);                     \
      kpA += 65536; kpB += 65536; vpA += 64; vpB += 64;                        \
    }                                                                          \
    f32x4 sa[4] = {};                                                          \
    __builtin_amdgcn_s_setprio(1);                                             \
    _Pragma("unroll") for (int nb = 0; nb < 4; ++nb) {                         \
      B8 kf0, kf1;                                                             \
      kf0.u = *(const u16x8*)(kbase0 + (BF)*8192 + nb * 2048);                 \
      kf1.u = *(const u16x8*)(kbase1 + (BF)*8192 + nb * 2048);                 \
      sa[nb] = MFMA_BF16(kf0.b, qa[0].b, sa[nb]);                              \
      sa[nb] = MFMA_BF16(kf1.b, qa[1].b, sa[nb]);                              \
    }                                                                          \
    __builtin_amdgcn_s_setprio(0);                                             \
    float p[16];                                                               \
    _Pragma("unroll") for (int nb = 0; nb < 4; ++nb)                           \
        _Pragma("unroll") for (int j = 0; j < 4; ++j) {                        \
      float pe = __builtin_amdgcn_exp2f(sa[nb][j]);                            \
      if (DOMASK) {                                                            \
        int kv = nb * 16 + lg * 4 + j;                                         \
        if (kv > qrow) pe = 0.f;                                               \
      }                                                                        \
      p[nb * 4 + j] = pe;                                                      \
    }                                                                          \
    {                                                                          \
      union { u16x4 v; unsigned uu[2]; } pk;                                   \
      pk.uu[0] = cvt_pk_bf16(p[0], p[1]);                                      \
      pk.uu[1] = cvt_pk_bf16(p[2], p[3]);                                      \
      *(u16x4*)pw0 = pk.v;                                                     \
      pk.uu[0] = cvt_pk_bf16(p[4], p[5]);                                      \
      pk.uu[1] = cvt_pk_bf16(p[6], p[7]);                                      \
      *(u16x4*)pw1 = pk.v;                                                     \
      pk.uu[0] = cvt_pk_bf16(p[8], p[9]);                                      \
      pk.uu[1] = cvt_pk_bf16(p[10], p[11]);                                    \
      *(u16x4*)pw2 = pk.v;                                                     \
      pk.uu[0] = cvt_pk_bf16(p[12], p[13]);                                    \
      pk.uu[1] = cvt_pk_bf16(p[14], p[15]);                                    \
      *(u16x4*)pw3 = pk.v;                                                     \
    }                                                                          \
    lrun += ((p[0] + p[1]) + (p[2] + p[3])) + ((p[4] + p[5]) + (p[6] + p[7])) +\
            ((p[8] + p[9]) + (p[10] + p[11])) +                                \
            ((p[12] + p[13]) + (p[14] + p[15]));                               \
    B8 pa0, pa1;                                                               \
    pa0.u = *(const u16x8*)pr0;                                                \
    pa1.u = *(const u16x8*)pr1;                                                \
    __builtin_amdgcn_s_setprio(1);                                             \
    _Pragma("unroll") for (int nb = 0; nb < 4; ++nb) {                         \
      B8 vf0, vf1;                                                             \
      vf0.u = *(const u16x8*)(vbase0 + (BF)*8192 + nb * 2048);                 \
      vf1.u = *(const u16x8*)(vbase1 + (BF)*8192 + nb * 2048);                 \
      o[nb] = MFMA_BF16(pa0.b, vf0.b, o[nb]);                                  \
      o[nb] = MFMA_BF16(pa1.b, vf1.b, o[nb]);                                  \
    }                                                                          \
    __builtin_amdgcn_s_setprio(0);                                             \
  } while (0)

  int U = qt;  // tiles 0..U-1 unmasked, tile U masked (diagonal)
  int i = 0;
  for (; i + 2 <= U; i += 2) {
    ATTN_ITER(0, false, true);
    ATTN_ITER(1, false, true);
  }
  if (U & 1) {
    ATTN_ITER(0, false, true);   // index U-1 (even) -> buf 0, stages tile U
    ATTN_ITER(1, true, false);   // masked tile U in buf 1
  } else {
    ATTN_ITER(0, true, false);   // masked tile U in buf 0
  }
#undef ATTN_ITER

  // epilogue: reduce partial sums across the 4 lg-lanes of each q-row
  lrun += __shfl_xor(lrun, 16);
  lrun += __shfl_xor(lrun, 32);
  float inv[4];
#pragma unroll
  for (int j = 0; j < 4; ++j) {
    float lj = __shfl(lrun, (lane & 48) | (lg * 4 + j));
    inv[j] = 1.0f / lj;
  }
#pragma unroll
  for (int nb = 0; nb < 4; ++nb)
#pragma unroll
    for (int j = 0; j < 4; ++j) {
      int row = qt * 64 + w * 16 + lg * 4 + j;
      int col = h * 64 + nb * 16 + l16;
      Y[((size_t)b * S + row) * E + col] = f2bf(o[nb][j] * inv[j]);
    }
}

extern "C" void kernel_launch(void* const* d_in, const int* in_sizes, int n_in,
                              void* d_out, int out_size, void* d_ws,
                              size_t ws_size, hipStream_t stream) {
  const float* X = (const float*)d_in[0];
  const float* Wq = (const float*)d_in[1];
  const float* Wk = (const float*)d_in[2];
  const float* Wv = (const float*)d_in[3];
  const float* Wp = (const float*)d_in[4];
  const float* bp = (const float*)d_in[5];
  float* out = (float*)d_out;

  char* ws = (char*)d_ws;
  const size_t MB = 1ull << 20;
  u16* Xb = (u16*)(ws + 0 * MB);
  u16* Wqb = (u16*)(ws + 8 * MB);   // Wq,Wk,Wv contiguous -> fused [3072][1024]
  u16* Wkb = (u16*)(ws + 10 * MB);
  u16* Wvb = (u16*)(ws + 12 * MB);
  u16* Wpb = (u16*)(ws + 14 * MB);
  u16* Qb = (u16*)(ws + 16 * MB);
  u16* Kb = (u16*)(ws + 24 * MB);
  u16* VtB = (u16*)(ws + 32 * MB);  // Vt[b][h][64][2048]
  u16* Y1 = (u16*)(ws + 40 * MB);

  cast5_kernel<<<8192, 256, 0, stream>>>(X, Wq, Wk, Wv, Wp, Xb, Wqb, Wkb, Wvb, Wpb);
  gemm_qkv192<<<256, 512, 0, stream>>>(Xb, Wqb, Qb, Kb, VtB);
  attn_kernel<<<1024, 256, 0, stream>>>(Qb, Kb, VtB, Y1);
  gemm_proj_kernel<<<dim3(8, 32), 256, 0, stream>>>(Y1, Wpb, out, bp);
}